// Round 3
// baseline (253.066 us; speedup 1.0000x reference)
//
#include <hip/hip_runtime.h>

#define IMG   1024
#define TSW   32
#define TSH   16
#define XTW   40      // xt cols: global C0-4 .. C0+35 (16B-aligned f4 loads)
#define XTH   22      // xt rows: global R0-3 .. R0+18
#define SW    40      // padded stride for s1/s2
#define S1H   20      // s1 rows: global R0-2 .. R0+17, valid cols 0..35 (C0-2+c)
#define S2H   18      // s2 rows: global R0-1 .. R0+16, valid cols 0..33 (C0-1+c)

#define OUT1  (2*IMG*IMG)            // den_x1 offset (elements)
#define OUT2  (OUT1 + 6*IMG*IMG)     // den_x2 offset

__device__ __forceinline__ float sigf(float y) { return 1.0f / (1.0f + __expf(-y)); }

__device__ __forceinline__ void ld8(const float* p, float* w) {
    float4 A = *(const float4*)p;
    float4 B = *(const float4*)(p + 4);
    w[0]=A.x; w[1]=A.y; w[2]=A.z; w[3]=A.w;
    w[4]=B.x; w[5]=B.y; w[6]=B.z; w[7]=B.w;
}

// One encoder branch: halo load -> conv1 -> conv2 -> conv3 -> den write (+ pa/outfeature)
template<int BR>
__device__ __forceinline__ void do_branch(
    const float* __restrict__ xin,
    const float* __restrict__ w1, float b1,
    const float* __restrict__ w2, float b2,
    const float* __restrict__ w3, float b3,
    float* xt, float* s1, float* s2, const float* wc,
    int tid, int R0, int C0, bool edge,
    float pa[2][4][2], float* __restrict__ out)
{
    // ---------------- halo load ----------------
    if (!edge) {
        for (int it = tid; it < 660; it += 256) {          // 3ch x 22 rows x 10 f4-segs
            int ch  = it / 220;  int rem = it - ch * 220;
            int row = rem / 10;  int seg = rem - row * 10;
            float4 v = *(const float4*)(xin + ch * (IMG*IMG) + (R0 - 3 + row) * IMG + (C0 - 4) + seg * 4);
            *(float4*)(xt + ch * (XTH*XTW) + row * XTW + seg * 4) = v;
        }
    } else {
        for (int it = tid; it < 3 * XTH * XTW; it += 256) {
            int ch  = it / (XTH*XTW); int rem = it - ch * (XTH*XTW);
            int row = rem / XTW;      int col = rem - row * XTW;
            int gr = R0 - 3 + row, gc = C0 - 4 + col;
            float v = 0.0f;
            if ((unsigned)gr < (unsigned)IMG && (unsigned)gc < (unsigned)IMG)
                v = xin[ch * (IMG*IMG) + gr * IMG + gc];
            xt[it] = v;
        }
    }
    __syncthreads();

    // ---------------- stage 1: conv(3ch)+sigmoid -> s1 (20x36 valid) ----------------
    if (tid < 90) {                                        // 10 row-strips x 9 col-groups
        int r = tid / 9, cg = tid - r * 9, c4 = cg * 4;
        float acc[2][4];
#pragma unroll
        for (int q = 0; q < 2; ++q)
#pragma unroll
            for (int j = 0; j < 4; ++j) acc[q][j] = b1;
#pragma unroll
        for (int ch = 0; ch < 3; ++ch) {
            float w9[9];
#pragma unroll
            for (int i = 0; i < 9; ++i) w9[i] = w1[ch * 9 + i];
            const float* base = xt + ch * (XTH*XTW) + (2 * r) * XTW + c4;
#pragma unroll
            for (int dr = 0; dr < 4; ++dr) {
                float w8[8]; ld8(base + dr * XTW, w8);
#pragma unroll
                for (int q = 0; q < 2; ++q) {
                    const int dy = dr - q;
                    if (dy >= 0 && dy < 3) {
#pragma unroll
                        for (int j = 0; j < 4; ++j)
#pragma unroll
                            for (int dx = 0; dx < 3; ++dx)
                                acc[q][j] += w9[dy * 3 + dx] * w8[1 + j + dx];
                    }
                }
            }
        }
        int gr0 = R0 - 2 + 2 * r, gc0 = C0 - 2 + c4;
#pragma unroll
        for (int q = 0; q < 2; ++q) {
            bool rok = (unsigned)(gr0 + q) < (unsigned)IMG;
            float o[4];
#pragma unroll
            for (int j = 0; j < 4; ++j) {
                bool ok = rok && ((unsigned)(gc0 + j) < (unsigned)IMG);
                o[j] = ok ? sigf(acc[q][j]) : 0.0f;
            }
            *(float4*)(s1 + (2 * r + q) * SW + c4) = make_float4(o[0], o[1], o[2], o[3]);
        }
    }
    __syncthreads();

    // ---------------- stage 2: conv(3ch + s1)+sigmoid -> s2 (18x34 valid) ----------------
    if (tid < 81) {                                        // 9 x 9
        int r = tid / 9, cg = tid - r * 9, c4 = cg * 4;
        float acc[2][4];
#pragma unroll
        for (int q = 0; q < 2; ++q)
#pragma unroll
            for (int j = 0; j < 4; ++j) acc[q][j] = b2;
#pragma unroll
        for (int ch = 0; ch < 3; ++ch) {
            float w9[9];
#pragma unroll
            for (int i = 0; i < 9; ++i) w9[i] = w2[ch * 9 + i];
            const float* base = xt + ch * (XTH*XTW) + (2 * r + 1) * XTW + c4;
#pragma unroll
            for (int dr = 0; dr < 4; ++dr) {
                float w8[8]; ld8(base + dr * XTW, w8);
#pragma unroll
                for (int q = 0; q < 2; ++q) {
                    const int dy = dr - q;
                    if (dy >= 0 && dy < 3) {
#pragma unroll
                        for (int j = 0; j < 4; ++j)
#pragma unroll
                            for (int dx = 0; dx < 3; ++dx)
                                acc[q][j] += w9[dy * 3 + dx] * w8[2 + j + dx];
                    }
                }
            }
        }
        {
            float w9[9];
#pragma unroll
            for (int i = 0; i < 9; ++i) w9[i] = w2[27 + i];
            const float* base = s1 + (2 * r) * SW + c4;
#pragma unroll
            for (int dr = 0; dr < 4; ++dr) {
                float w8[8]; ld8(base + dr * SW, w8);
#pragma unroll
                for (int q = 0; q < 2; ++q) {
                    const int dy = dr - q;
                    if (dy >= 0 && dy < 3) {
#pragma unroll
                        for (int j = 0; j < 4; ++j)
#pragma unroll
                            for (int dx = 0; dx < 3; ++dx)
                                acc[q][j] += w9[dy * 3 + dx] * w8[j + dx];
                    }
                }
            }
        }
        int gr0 = R0 - 1 + 2 * r, gc0 = C0 - 1 + c4;
#pragma unroll
        for (int q = 0; q < 2; ++q) {
            bool rok = (unsigned)(gr0 + q) < (unsigned)IMG;
            float o[4];
#pragma unroll
            for (int j = 0; j < 4; ++j) {
                bool ok = rok && ((unsigned)(gc0 + j) < (unsigned)IMG);
                o[j] = ok ? sigf(acc[q][j]) : 0.0f;
            }
            *(float4*)(s2 + (2 * r + q) * SW + c4) = make_float4(o[0], o[1], o[2], o[3]);
        }
    }
    __syncthreads();

    // ---------------- stage 3 + gather + outputs (32x16 interior px) ----------------
    if (tid < 64) {                                        // 8 row-strips x 8 col-groups
        int r = tid >> 3, cg = tid & 7, c4 = cg * 4;
        float acc[2][4];
#pragma unroll
        for (int q = 0; q < 2; ++q)
#pragma unroll
            for (int j = 0; j < 4; ++j) acc[q][j] = b3;
#pragma unroll
        for (int ch = 0; ch < 3; ++ch) {                   // x channels: window cols c4+2..c4+9
            float w9[9];
#pragma unroll
            for (int i = 0; i < 9; ++i) w9[i] = w3[ch * 9 + i];
            const float* base = xt + ch * (XTH*XTW) + (2 * r + 2) * XTW + c4;
#pragma unroll
            for (int dr = 0; dr < 4; ++dr) {
                const float* p = base + dr * XTW;
                float2 A  = *(const float2*)(p + 2);
                float4 B  = *(const float4*)(p + 4);
                float2 Cx = *(const float2*)(p + 8);
                float w8[8] = {A.x, A.y, B.x, B.y, B.z, B.w, Cx.x, Cx.y};
#pragma unroll
                for (int q = 0; q < 2; ++q) {
                    const int dy = dr - q;
                    if (dy >= 0 && dy < 3) {
#pragma unroll
                        for (int j = 0; j < 4; ++j)
#pragma unroll
                            for (int dx = 0; dx < 3; ++dx)
                                acc[q][j] += w9[dy * 3 + dx] * w8[j + 1 + dx];
                    }
                }
            }
        }
        {                                                  // s1 channel
            float w9[9];
#pragma unroll
            for (int i = 0; i < 9; ++i) w9[i] = w3[27 + i];
            const float* base = s1 + (2 * r + 1) * SW + c4;
#pragma unroll
            for (int dr = 0; dr < 4; ++dr) {
                float w8[8]; ld8(base + dr * SW, w8);
#pragma unroll
                for (int q = 0; q < 2; ++q) {
                    const int dy = dr - q;
                    if (dy >= 0 && dy < 3) {
#pragma unroll
                        for (int j = 0; j < 4; ++j)
#pragma unroll
                            for (int dx = 0; dx < 3; ++dx)
                                acc[q][j] += w9[dy * 3 + dx] * w8[1 + j + dx];
                    }
                }
            }
        }
        {                                                  // s2 channel
            float w9[9];
#pragma unroll
            for (int i = 0; i < 9; ++i) w9[i] = w3[36 + i];
            const float* base = s2 + (2 * r) * SW + c4;
#pragma unroll
            for (int dr = 0; dr < 4; ++dr) {
                float w8[8]; ld8(base + dr * SW, w8);
#pragma unroll
                for (int q = 0; q < 2; ++q) {
                    const int dy = dr - q;
                    if (dy >= 0 && dy < 3) {
#pragma unroll
                        for (int j = 0; j < 4; ++j)
#pragma unroll
                            for (int dx = 0; dx < 3; ++dx)
                                acc[q][j] += w9[dy * 3 + dx] * w8[j + dx];
                    }
                }
            }
        }

#pragma unroll
        for (int q = 0; q < 2; ++q) {
            float cur[4][6];
#pragma unroll
            for (int ch = 0; ch < 3; ++ch) {
                float4 g = *(const float4*)(xt + ch * (XTH*XTW) + (2 * r + 3 + q) * XTW + c4 + 4);
                cur[0][ch] = g.x; cur[1][ch] = g.y; cur[2][ch] = g.z; cur[3][ch] = g.w;
            }
            {
                float2 a = *(const float2*)(s1 + (2 * r + 2 + q) * SW + c4 + 2);
                float2 b = *(const float2*)(s1 + (2 * r + 2 + q) * SW + c4 + 4);
                cur[0][3] = a.x; cur[1][3] = a.y; cur[2][3] = b.x; cur[3][3] = b.y;
            }
            {
                float4 a = *(const float4*)(s2 + (2 * r + 1 + q) * SW + c4);
                float  e = s2[(2 * r + 1 + q) * SW + c4 + 4];
                cur[0][4] = a.y; cur[1][4] = a.z; cur[2][4] = a.w; cur[3][4] = e;
            }
#pragma unroll
            for (int j = 0; j < 4; ++j) cur[j][5] = sigf(acc[q][j]);

            const int pix0 = (R0 + 2 * r + q) * IMG + C0 + c4;
            const int denOff = (BR == 0) ? OUT1 : OUT2;
#pragma unroll
            for (int j = 0; j < 4; ++j) {
                float* pd = out + denOff + (pix0 + j) * 6;
                *(float2*)(pd)     = make_float2(cur[j][0], cur[j][1]);
                *(float2*)(pd + 2) = make_float2(cur[j][2], cur[j][3]);
                *(float2*)(pd + 4) = make_float2(cur[j][4], cur[j][5]);
            }
            if (BR == 0) {
#pragma unroll
                for (int j = 0; j < 4; ++j) {
                    float p0 = 0.0f, p1 = 0.0f;
#pragma unroll
                    for (int ch = 0; ch < 6; ++ch) {
                        p0 += wc[ch]     * cur[j][ch];
                        p1 += wc[6 + ch] * cur[j][ch];
                    }
                    pa[q][j][0] = p0; pa[q][j][1] = p1;
                }
            } else {
#pragma unroll
                for (int j = 0; j < 4; ++j) {
                    float o0 = pa[q][j][0] + wc[12];
                    float o1 = pa[q][j][1] + wc[13];
#pragma unroll
                    for (int ch = 0; ch < 6; ++ch) {
                        o0 -= wc[ch]     * cur[j][ch];
                        o1 -= wc[6 + ch] * cur[j][ch];
                    }
                    *(float2*)(out + (pix0 + j) * 2) = make_float2(o0, o1);
                }
            }
        }
    }
    __syncthreads();   // protect xt/s1/s2 before next branch reuses them
}

__global__ __launch_bounds__(256, 6)
void unet_fused(const float* __restrict__ x, const float* __restrict__ x2,
                const float* __restrict__ w1a, const float* __restrict__ b1a,
                const float* __restrict__ w2a, const float* __restrict__ b2a,
                const float* __restrict__ w3a, const float* __restrict__ b3a,
                const float* __restrict__ w1b, const float* __restrict__ b1b,
                const float* __restrict__ w2b, const float* __restrict__ b2b,
                const float* __restrict__ w3b, const float* __restrict__ b3b,
                const float* __restrict__ lw1, const float* __restrict__ lb1,
                const float* __restrict__ lw2, const float* __restrict__ lb2,
                float* __restrict__ out)
{
    __shared__ float xt[3 * XTH * XTW];
    __shared__ float s1[S1H * SW];
    __shared__ float s2[S2H * SW];
    __shared__ float wc[14];

    const int tid = threadIdx.x;

    // XCD-aware swizzle: each XCD owns a contiguous band of 256 blocks (8 tile-rows)
    int lin = blockIdx.y * gridDim.x + blockIdx.x;          // 0..2047
    int nid = (lin & 7) * 256 + (lin >> 3);
    int bx = nid & 31, by = nid >> 5;
    const int R0 = by * TSH, C0 = bx * TSW;
    const bool edge = (bx == 0) | (bx == 31) | (by == 0) | (by == 63);

    // collapsed 6->2 affine map (hidden under halo load; barrier inside do_branch covers)
    if (tid < 12) {
        int o = tid / 6, ch = tid - o * 6;
        float acc = 0.0f;
        for (int k = 0; k < 128; ++k) acc += lw2[o * 128 + k] * lw1[k * 6 + ch];
        wc[tid] = acc;
    } else if (tid < 14) {
        int o = tid - 12;
        float acc = lb2[o];
        for (int k = 0; k < 128; ++k) acc += lw2[o * 128 + k] * lb1[k];
        wc[tid] = acc;
    }

    float pa[2][4][2];

    do_branch<0>(x,  w1a, b1a[0], w2a, b2a[0], w3a, b3a[0],
                 xt, s1, s2, wc, tid, R0, C0, edge, pa, out);
    do_branch<1>(x2, w1b, b1b[0], w2b, b2b[0], w3b, b3b[0],
                 xt, s1, s2, wc, tid, R0, C0, edge, pa, out);
}

extern "C" void kernel_launch(void* const* d_in, const int* in_sizes, int n_in,
                              void* d_out, int out_size, void* d_ws, size_t ws_size,
                              hipStream_t stream) {
    const float* x   = (const float*)d_in[0];
    const float* x2  = (const float*)d_in[1];
    const float* w1a = (const float*)d_in[2];
    const float* b1a = (const float*)d_in[3];
    const float* w2a = (const float*)d_in[4];
    const float* b2a = (const float*)d_in[5];
    const float* w3a = (const float*)d_in[6];
    const float* b3a = (const float*)d_in[7];
    const float* w1b = (const float*)d_in[8];
    const float* b1b = (const float*)d_in[9];
    const float* w2b = (const float*)d_in[10];
    const float* b2b = (const float*)d_in[11];
    const float* w3b = (const float*)d_in[12];
    const float* b3b = (const float*)d_in[13];
    const float* lw1 = (const float*)d_in[14];
    const float* lb1 = (const float*)d_in[15];
    const float* lw2 = (const float*)d_in[16];
    const float* lb2 = (const float*)d_in[17];
    float* out = (float*)d_out;

    dim3 grid(IMG / TSW, IMG / TSH);   // 32 x 64 = 2048 blocks
    unet_fused<<<grid, 256, 0, stream>>>(x, x2,
                                         w1a, b1a, w2a, b2a, w3a, b3a,
                                         w1b, b1b, w2b, b2b, w3b, b3b,
                                         lw1, lb1, lw2, lb2, out);
}

// Round 4
// 233.834 us; speedup vs baseline: 1.0822x; 1.0822x over previous
//
#include <hip/hip_runtime.h>

#define IMG  1024
#define TS   32
#define XT   38            // halo tile: image rows/cols R0-3 .. R0+34
#define XTA  (XT*XT)
#define S1R  12            // per-wave s1 strip: tile rows 8w-2 .. 8w+9
#define S1C  36            // tile cols -2 .. 33
#define S2R  10            // per-wave s2 strip: tile rows 8w-1 .. 8w+8
#define S2C  34            // tile cols -1 .. 32
#define OUT1 (2*IMG*IMG)
#define OUT2 (OUT1 + 6*IMG*IMG)

__device__ __forceinline__ float sigf(float y) { return 1.0f / (1.0f + __expf(-y)); }

__global__ __launch_bounds__(256, 4)
void unet_fused(const float* __restrict__ x, const float* __restrict__ x2,
                const float* __restrict__ w1a, const float* __restrict__ b1a,
                const float* __restrict__ w2a, const float* __restrict__ b2a,
                const float* __restrict__ w3a, const float* __restrict__ b3a,
                const float* __restrict__ w1b, const float* __restrict__ b1b,
                const float* __restrict__ w2b, const float* __restrict__ b2b,
                const float* __restrict__ w3b, const float* __restrict__ b3b,
                const float* __restrict__ lw1, const float* __restrict__ lb1,
                const float* __restrict__ lw2, const float* __restrict__ lb2,
                float* __restrict__ out)
{
    __shared__ float xt[3][XTA];          // 17.3 KB, shared by all waves (read-only after barrier)
    __shared__ float s1[4][S1R * S1C];    // 6.9 KB, wave-private strips
    __shared__ float s2[4][S2R * S2C];    // 5.4 KB, wave-private strips
    __shared__ float wc[14];              // collapsed 6->2 affine

    const int tid  = threadIdx.x;
    const int wv   = tid >> 6;
    const int lane = tid & 63;
    const int R0 = blockIdx.y * TS, C0 = blockIdx.x * TS;

    // collapsed linear map (before first barrier; visible to all after it)
    if (tid < 12) {
        int o = tid / 6, ch = tid - o * 6;
        float acc = 0.0f;
        for (int k = 0; k < 128; ++k) acc += lw2[o * 128 + k] * lw1[k * 6 + ch];
        wc[tid] = acc;
    } else if (tid < 14) {
        int o = tid - 12;
        float acc = lb2[o];
        for (int k = 0; k < 128; ++k) acc += lw2[o * 128 + k] * lb1[k];
        wc[tid] = acc;
    }

    const float* XS[2] = {x, x2};
    const float* W1[2] = {w1a, w1b};
    const float* W2[2] = {w2a, w2b};
    const float* W3[2] = {w3a, w3b};
    const float* B1[2] = {b1a, b1b};
    const float* B2[2] = {b2a, b2b};
    const float* B3[2] = {b3a, b3b};

    float pa[4][2];                       // branch-a pre-projected outfeature terms
    float* s1w = s1[wv];
    float* s2w = s2[wv];

    const int c_out = lane & 31;          // output column within tile
    const int rg    = lane >> 5;          // 0/1: which 4-row group of the wave's 8 rows
    const int tr0   = 8 * wv + rg * 4;    // first output tile-row for this thread

#pragma unroll
    for (int br = 0; br < 2; ++br) {
        __syncthreads();                  // xt safe to overwrite (prev branch reads done)
        const float* xin = XS[br];
        for (int it = tid; it < 3 * XTA; it += 256) {
            int ch = it / XTA, rem = it - ch * XTA;
            int r = rem / XT, c = rem - r * XT;
            int gr = R0 - 3 + r, gc = C0 - 3 + c;
            float v = 0.0f;
            if ((unsigned)gr < (unsigned)IMG && (unsigned)gc < (unsigned)IMG)
                v = xin[ch * (IMG * IMG) + gr * IMG + gc];
            xt[ch][rem] = v;
        }
        __syncthreads();                  // halo ready — last barrier until next branch

        // ---- stage 1: wave-private 12x36 strip, one column per lane, rolling window ----
        if (lane < S1C) {
            const int sc = lane;
            const float b1 = B1[br][0];
            float acc[S1R];
#pragma unroll
            for (int q = 0; q < S1R; ++q) acc[q] = b1;
#pragma unroll
            for (int ch = 0; ch < 3; ++ch) {
                float w9[9];
#pragma unroll
                for (int i = 0; i < 9; ++i) w9[i] = W1[br][ch * 9 + i];
                const float* xp = &xt[ch][(8 * wv) * XT + sc];
#pragma unroll
                for (int r = 0; r < 14; ++r) {
                    float a0 = xp[0], a1 = xp[1], a2 = xp[2];
                    xp += XT;
#pragma unroll
                    for (int dy = 0; dy < 3; ++dy) {
                        int q = r - dy;
                        if (q >= 0 && q < S1R)
                            acc[q] += w9[dy * 3] * a0 + w9[dy * 3 + 1] * a1 + w9[dy * 3 + 2] * a2;
                    }
                }
            }
            const int gcol = C0 - 2 + sc;
            const bool cok = (unsigned)gcol < (unsigned)IMG;
            const int grow0 = R0 + 8 * wv - 2;
#pragma unroll
            for (int q = 0; q < S1R; ++q) {
                bool ok = cok && ((unsigned)(grow0 + q) < (unsigned)IMG);
                s1w[q * S1C + sc] = ok ? sigf(acc[q]) : 0.0f;
            }
        }

        // ---- stage 2: wave-private 10x34 strip ----
        if (lane < S2C) {
            const int sc = lane;
            const float b2 = B2[br][0];
            float acc[S2R];
#pragma unroll
            for (int q = 0; q < S2R; ++q) acc[q] = b2;
#pragma unroll
            for (int ch = 0; ch < 3; ++ch) {
                float w9[9];
#pragma unroll
                for (int i = 0; i < 9; ++i) w9[i] = W2[br][ch * 9 + i];
                const float* xp = &xt[ch][(8 * wv + 1) * XT + (sc + 1)];
#pragma unroll
                for (int r = 0; r < 12; ++r) {
                    float a0 = xp[0], a1 = xp[1], a2 = xp[2];
                    xp += XT;
#pragma unroll
                    for (int dy = 0; dy < 3; ++dy) {
                        int q = r - dy;
                        if (q >= 0 && q < S2R)
                            acc[q] += w9[dy * 3] * a0 + w9[dy * 3 + 1] * a1 + w9[dy * 3 + 2] * a2;
                    }
                }
            }
            {
                float w9[9];
#pragma unroll
                for (int i = 0; i < 9; ++i) w9[i] = W2[br][27 + i];
                const float* sp = &s1w[sc];
#pragma unroll
                for (int r = 0; r < 12; ++r) {
                    float a0 = sp[0], a1 = sp[1], a2 = sp[2];
                    sp += S1C;
#pragma unroll
                    for (int dy = 0; dy < 3; ++dy) {
                        int q = r - dy;
                        if (q >= 0 && q < S2R)
                            acc[q] += w9[dy * 3] * a0 + w9[dy * 3 + 1] * a1 + w9[dy * 3 + 2] * a2;
                    }
                }
            }
            const int gcol = C0 - 1 + sc;
            const bool cok = (unsigned)gcol < (unsigned)IMG;
            const int grow0 = R0 + 8 * wv - 1;
#pragma unroll
            for (int q = 0; q < S2R; ++q) {
                bool ok = cok && ((unsigned)(grow0 + q) < (unsigned)IMG);
                s2w[q * S2C + sc] = ok ? sigf(acc[q]) : 0.0f;
            }
        }

        // ---- stage 3 + gather + outputs: all 64 lanes, 4 px per lane ----
        {
            const int c = c_out;
            const float b3v = B3[br][0];
            float acc[4] = {b3v, b3v, b3v, b3v};
#pragma unroll
            for (int ch = 0; ch < 3; ++ch) {
                float w9[9];
#pragma unroll
                for (int i = 0; i < 9; ++i) w9[i] = W3[br][ch * 9 + i];
                const float* xp = &xt[ch][(tr0 + 2) * XT + (c + 2)];
#pragma unroll
                for (int r = 0; r < 6; ++r) {
                    float a0 = xp[0], a1 = xp[1], a2 = xp[2];
                    xp += XT;
#pragma unroll
                    for (int dy = 0; dy < 3; ++dy) {
                        int q = r - dy;
                        if (q >= 0 && q < 4)
                            acc[q] += w9[dy * 3] * a0 + w9[dy * 3 + 1] * a1 + w9[dy * 3 + 2] * a2;
                    }
                }
            }
            {
                float w9[9];
#pragma unroll
                for (int i = 0; i < 9; ++i) w9[i] = W3[br][27 + i];
                const float* sp = &s1w[(rg * 4 + 1) * S1C + (c + 1)];
#pragma unroll
                for (int r = 0; r < 6; ++r) {
                    float a0 = sp[0], a1 = sp[1], a2 = sp[2];
                    sp += S1C;
#pragma unroll
                    for (int dy = 0; dy < 3; ++dy) {
                        int q = r - dy;
                        if (q >= 0 && q < 4)
                            acc[q] += w9[dy * 3] * a0 + w9[dy * 3 + 1] * a1 + w9[dy * 3 + 2] * a2;
                    }
                }
            }
            {
                float w9[9];
#pragma unroll
                for (int i = 0; i < 9; ++i) w9[i] = W3[br][36 + i];
                const float* sp = &s2w[(rg * 4) * S2C + c];
#pragma unroll
                for (int r = 0; r < 6; ++r) {
                    float a0 = sp[0], a1 = sp[1], a2 = sp[2];
                    sp += S2C;
#pragma unroll
                    for (int dy = 0; dy < 3; ++dy) {
                        int q = r - dy;
                        if (q >= 0 && q < 4)
                            acc[q] += w9[dy * 3] * a0 + w9[dy * 3 + 1] * a1 + w9[dy * 3 + 2] * a2;
                    }
                }
            }

            float cur[4][6];
#pragma unroll
            for (int rr = 0; rr < 4; ++rr) {
#pragma unroll
                for (int ch = 0; ch < 3; ++ch)
                    cur[rr][ch] = xt[ch][(tr0 + 3 + rr) * XT + (c + 3)];
                cur[rr][3] = s1w[(rg * 4 + 2 + rr) * S1C + (c + 2)];
                cur[rr][4] = s2w[(rg * 4 + 1 + rr) * S2C + (c + 1)];
                cur[rr][5] = sigf(acc[rr]);
            }

            // den writes: R2-proven pattern (all 256 threads, 24B/px contiguous per lane)
            const int denOff = (br == 0) ? OUT1 : OUT2;
#pragma unroll
            for (int rr = 0; rr < 4; ++rr) {
                int pix = (R0 + tr0 + rr) * IMG + C0 + c;
                float* pd = out + denOff + pix * 6;
#pragma unroll
                for (int ch = 0; ch < 6; ++ch) pd[ch] = cur[rr][ch];
            }
            if (br == 0) {
#pragma unroll
                for (int rr = 0; rr < 4; ++rr) {
                    float p0 = 0.0f, p1 = 0.0f;
#pragma unroll
                    for (int ch = 0; ch < 6; ++ch) {
                        p0 += wc[ch]     * cur[rr][ch];
                        p1 += wc[6 + ch] * cur[rr][ch];
                    }
                    pa[rr][0] = p0; pa[rr][1] = p1;
                }
            } else {
#pragma unroll
                for (int rr = 0; rr < 4; ++rr) {
                    float o0 = pa[rr][0] + wc[12];
                    float o1 = pa[rr][1] + wc[13];
#pragma unroll
                    for (int ch = 0; ch < 6; ++ch) {
                        o0 -= wc[ch]     * cur[rr][ch];
                        o1 -= wc[6 + ch] * cur[rr][ch];
                    }
                    int pix = (R0 + tr0 + rr) * IMG + C0 + c;
                    out[pix * 2]     = o0;
                    out[pix * 2 + 1] = o1;
                }
            }
        }
    }
}

extern "C" void kernel_launch(void* const* d_in, const int* in_sizes, int n_in,
                              void* d_out, int out_size, void* d_ws, size_t ws_size,
                              hipStream_t stream) {
    const float* x   = (const float*)d_in[0];
    const float* x2  = (const float*)d_in[1];
    const float* w1a = (const float*)d_in[2];
    const float* b1a = (const float*)d_in[3];
    const float* w2a = (const float*)d_in[4];
    const float* b2a = (const float*)d_in[5];
    const float* w3a = (const float*)d_in[6];
    const float* b3a = (const float*)d_in[7];
    const float* w1b = (const float*)d_in[8];
    const float* b1b = (const float*)d_in[9];
    const float* w2b = (const float*)d_in[10];
    const float* b2b = (const float*)d_in[11];
    const float* w3b = (const float*)d_in[12];
    const float* b3b = (const float*)d_in[13];
    const float* lw1 = (const float*)d_in[14];
    const float* lb1 = (const float*)d_in[15];
    const float* lw2 = (const float*)d_in[16];
    const float* lb2 = (const float*)d_in[17];
    float* out = (float*)d_out;

    dim3 grid(IMG / TS, IMG / TS);   // 32 x 32 = 1024 blocks
    unet_fused<<<grid, 256, 0, stream>>>(x, x2,
                                         w1a, b1a, w2a, b2a, w3a, b3a,
                                         w1b, b1b, w2b, b2b, w3b, b3b,
                                         lw1, lb1, lw2, lb2, out);
}

// Round 5
// 153.933 us; speedup vs baseline: 1.6440x; 1.5191x over previous
//
#include <hip/hip_runtime.h>

#define IMG  1024
#define TSW  32
#define TSH  16
#define XTH  22            // xt rows: global R0-3 .. R0+18
#define XTW  40            // xt cols: global C0-4 .. C0+35 (16B-aligned f4 loads)
#define XTA  (XTH*XTW)
#define S1H  20            // s1 rows: global R0-2 .. R0+17
#define S1W  36            // s1 cols: global C0-2 .. C0+33
#define S2H  18            // s2 rows: global R0-1 .. R0+16
#define S2W  34            // s2 cols: global C0-1 .. C0+32
#define OUT1 (2*IMG*IMG)
#define OUT2 (OUT1 + 6*IMG*IMG)

__device__ __forceinline__ float sigf(float y) { return 1.0f / (1.0f + __expf(-y)); }

// One branch of the network. BR=0: writes den_x1 + pa=Wc*a to ws. BR=1: writes den_x2 + outfeature.
template<int BR>
__global__ __launch_bounds__(256, 8)
void unet_half(const float* __restrict__ xin,
               const float* __restrict__ w1, const float* __restrict__ b1p,
               const float* __restrict__ w2, const float* __restrict__ b2p,
               const float* __restrict__ w3, const float* __restrict__ b3p,
               const float* __restrict__ lw1, const float* __restrict__ lb1,
               const float* __restrict__ lw2, const float* __restrict__ lb2,
               float* __restrict__ pa, float* __restrict__ out)
{
    __shared__ float xt[3 * XTA];      // 10560 B
    __shared__ float s1[S1H * S1W];    //  2880 B
    __shared__ float s2[S2H * S2W];    //  2448 B
    __shared__ float wc[14];           // collapsed 6->2 affine

    const int tid = threadIdx.x;

    // XCD-aware swizzle (2048 blocks, 256 per XCD -> 8 contiguous tile-rows each)
    int lin = blockIdx.y * gridDim.x + blockIdx.x;          // 0..2047
    int nid = (lin & 7) * 256 + (lin >> 3);
    int bx = nid & 31, by = nid >> 5;                       // bx 0..31, by 0..63
    const int R0 = by * TSH, C0 = bx * TSW;
    const bool edge = (bx == 0) | (bx == 31) | (by == 0) | (by == 63);

    // collapsed linear map (runs before first barrier)
    if (tid < 12) {
        int o = tid / 6, ch = tid - o * 6;
        float acc = 0.0f;
        for (int k = 0; k < 128; ++k) acc += lw2[o * 128 + k] * lw1[k * 6 + ch];
        wc[tid] = acc;
    } else if (tid < 14) {
        int o = tid - 12;
        float acc = lb2[o];
        for (int k = 0; k < 128; ++k) acc += lw2[o * 128 + k] * lb1[k];
        wc[tid] = acc;
    }

    // ---------------- halo load ----------------
    if (!edge) {
        for (int it = tid; it < 3 * XTH * 10; it += 256) {          // f4 segments
            int ch = it / (XTH * 10); int rem = it - ch * (XTH * 10);
            int row = rem / 10, seg = rem - row * 10;
            float4 v = *(const float4*)(xin + ch * (IMG * IMG) + (R0 - 3 + row) * IMG + (C0 - 4) + seg * 4);
            *(float4*)(xt + ch * XTA + row * XTW + seg * 4) = v;
        }
    } else {
        for (int it = tid; it < 3 * XTA; it += 256) {
            int ch = it / XTA; int rem = it - ch * XTA;
            int row = rem / XTW, col = rem - row * XTW;
            int gr = R0 - 3 + row, gc = C0 - 4 + col;
            float v = 0.0f;
            if ((unsigned)gr < (unsigned)IMG && (unsigned)gc < (unsigned)IMG)
                v = xin[ch * (IMG * IMG) + gr * IMG + gc];
            xt[it] = v;
        }
    }
    __syncthreads();

    const float b1 = b1p[0], b2 = b2p[0], b3 = b3p[0];

    // ---------------- stage 1: conv(3ch)+sigmoid -> s1 (20x36), 252 items of 3-row strips ----------------
    if (tid < 252) {
        int rs = tid / S1W, sc = tid - rs * S1W;            // rs 0..6
        int r0 = rs * 3;
        float acc[3] = {b1, b1, b1};
#pragma unroll
        for (int ch = 0; ch < 3; ++ch) {
            float w9[9];
#pragma unroll
            for (int i = 0; i < 9; ++i) w9[i] = w1[ch * 9 + i];
#pragma unroll
            for (int r = 0; r < 5; ++r) {
                int rr = r0 + r; if (rr > XTH - 1) rr = XTH - 1;    // rs=6 tail clamp (acc[2] unused)
                const float* p = &xt[ch * XTA + rr * XTW + sc + 1];
                float a0 = p[0], a1 = p[1], a2 = p[2];
#pragma unroll
                for (int dy = 0; dy < 3; ++dy) {
                    int q = r - dy;
                    if (q >= 0 && q < 3)
                        acc[q] += w9[dy * 3] * a0 + w9[dy * 3 + 1] * a1 + w9[dy * 3 + 2] * a2;
                }
            }
        }
        int gc1 = C0 - 2 + sc;
        bool cok = (unsigned)gc1 < (unsigned)IMG;
#pragma unroll
        for (int q = 0; q < 3; ++q) {
            int sr = r0 + q;
            if (sr < S1H) {
                int gr1 = R0 - 2 + sr;
                bool ok = cok && ((unsigned)gr1 < (unsigned)IMG);
                s1[sr * S1W + sc] = ok ? sigf(acc[q]) : 0.0f;
            }
        }
    }
    __syncthreads();

    // ---------------- stage 2: conv(3ch+s1)+sigmoid -> s2 (18x34), 204 items of 3-row strips ----------------
    if (tid < 204) {
        int rs = tid / S2W, sc = tid - rs * S2W;            // rs 0..5 exact
        int r0 = rs * 3;
        float acc[3] = {b2, b2, b2};
#pragma unroll
        for (int ch = 0; ch < 3; ++ch) {
            float w9[9];
#pragma unroll
            for (int i = 0; i < 9; ++i) w9[i] = w2[ch * 9 + i];
#pragma unroll
            for (int r = 0; r < 5; ++r) {
                const float* p = &xt[ch * XTA + (r0 + 1 + r) * XTW + sc + 2];
                float a0 = p[0], a1 = p[1], a2 = p[2];
#pragma unroll
                for (int dy = 0; dy < 3; ++dy) {
                    int q = r - dy;
                    if (q >= 0 && q < 3)
                        acc[q] += w9[dy * 3] * a0 + w9[dy * 3 + 1] * a1 + w9[dy * 3 + 2] * a2;
                }
            }
        }
        {
            float w9[9];
#pragma unroll
            for (int i = 0; i < 9; ++i) w9[i] = w2[27 + i];
#pragma unroll
            for (int r = 0; r < 5; ++r) {
                const float* p = &s1[(r0 + r) * S1W + sc];
                float a0 = p[0], a1 = p[1], a2 = p[2];
#pragma unroll
                for (int dy = 0; dy < 3; ++dy) {
                    int q = r - dy;
                    if (q >= 0 && q < 3)
                        acc[q] += w9[dy * 3] * a0 + w9[dy * 3 + 1] * a1 + w9[dy * 3 + 2] * a2;
                }
            }
        }
        int gc2 = C0 - 1 + sc;
        bool cok = (unsigned)gc2 < (unsigned)IMG;
#pragma unroll
        for (int q = 0; q < 3; ++q) {
            int sr = r0 + q;
            int gr2 = R0 - 1 + sr;
            bool ok = cok && ((unsigned)gr2 < (unsigned)IMG);
            s2[sr * S2W + sc] = ok ? sigf(acc[q]) : 0.0f;
        }
    }
    __syncthreads();

    // ---------------- stage 3 + gather + writes: 256 items of 2-row strips (exact) ----------------
    {
        const int c = tid & 31, rs = tid >> 5;              // rs 0..7
        const int r0 = rs * 2;
        float acc[2] = {b3, b3};
#pragma unroll
        for (int ch = 0; ch < 3; ++ch) {
            float w9[9];
#pragma unroll
            for (int i = 0; i < 9; ++i) w9[i] = w3[ch * 9 + i];
#pragma unroll
            for (int r = 0; r < 4; ++r) {
                const float* p = &xt[ch * XTA + (r0 + 2 + r) * XTW + c + 3];
                float a0 = p[0], a1 = p[1], a2 = p[2];
#pragma unroll
                for (int dy = 0; dy < 3; ++dy) {
                    int q = r - dy;
                    if (q >= 0 && q < 2)
                        acc[q] += w9[dy * 3] * a0 + w9[dy * 3 + 1] * a1 + w9[dy * 3 + 2] * a2;
                }
            }
        }
        {
            float w9[9];
#pragma unroll
            for (int i = 0; i < 9; ++i) w9[i] = w3[27 + i];
#pragma unroll
            for (int r = 0; r < 4; ++r) {
                const float* p = &s1[(r0 + 1 + r) * S1W + c + 1];
                float a0 = p[0], a1 = p[1], a2 = p[2];
#pragma unroll
                for (int dy = 0; dy < 3; ++dy) {
                    int q = r - dy;
                    if (q >= 0 && q < 2)
                        acc[q] += w9[dy * 3] * a0 + w9[dy * 3 + 1] * a1 + w9[dy * 3 + 2] * a2;
                }
            }
        }
        {
            float w9[9];
#pragma unroll
            for (int i = 0; i < 9; ++i) w9[i] = w3[36 + i];
#pragma unroll
            for (int r = 0; r < 4; ++r) {
                const float* p = &s2[(r0 + r) * S2W + c];
                float a0 = p[0], a1 = p[1], a2 = p[2];
#pragma unroll
                for (int dy = 0; dy < 3; ++dy) {
                    int q = r - dy;
                    if (q >= 0 && q < 2)
                        acc[q] += w9[dy * 3] * a0 + w9[dy * 3 + 1] * a1 + w9[dy * 3 + 2] * a2;
                }
            }
        }

#pragma unroll
        for (int q = 0; q < 2; ++q) {
            float cur[6];
#pragma unroll
            for (int ch = 0; ch < 3; ++ch)
                cur[ch] = xt[ch * XTA + (r0 + 3 + q) * XTW + c + 4];
            cur[3] = s1[(r0 + 2 + q) * S1W + c + 2];
            cur[4] = s2[(r0 + 1 + q) * S2W + c + 1];
            cur[5] = sigf(acc[q]);

            const int pix = (R0 + r0 + q) * IMG + C0 + c;
            float* pd = out + ((BR == 0) ? OUT1 : OUT2) + pix * 6;
#pragma unroll
            for (int ch = 0; ch < 6; ++ch) pd[ch] = cur[ch];

            if (BR == 0) {
                float p0 = 0.0f, p1 = 0.0f;
#pragma unroll
                for (int ch = 0; ch < 6; ++ch) {
                    p0 += wc[ch]     * cur[ch];
                    p1 += wc[6 + ch] * cur[ch];
                }
                pa[pix * 2]     = p0;
                pa[pix * 2 + 1] = p1;
            } else {
                float o0 = pa[pix * 2]     + wc[12];
                float o1 = pa[pix * 2 + 1] + wc[13];
#pragma unroll
                for (int ch = 0; ch < 6; ++ch) {
                    o0 -= wc[ch]     * cur[ch];
                    o1 -= wc[6 + ch] * cur[ch];
                }
                out[pix * 2]     = o0;
                out[pix * 2 + 1] = o1;
            }
        }
    }
}

extern "C" void kernel_launch(void* const* d_in, const int* in_sizes, int n_in,
                              void* d_out, int out_size, void* d_ws, size_t ws_size,
                              hipStream_t stream) {
    const float* x   = (const float*)d_in[0];
    const float* x2  = (const float*)d_in[1];
    const float* w1a = (const float*)d_in[2];
    const float* b1a = (const float*)d_in[3];
    const float* w2a = (const float*)d_in[4];
    const float* b2a = (const float*)d_in[5];
    const float* w3a = (const float*)d_in[6];
    const float* b3a = (const float*)d_in[7];
    const float* w1b = (const float*)d_in[8];
    const float* b1b = (const float*)d_in[9];
    const float* w2b = (const float*)d_in[10];
    const float* b2b = (const float*)d_in[11];
    const float* w3b = (const float*)d_in[12];
    const float* b3b = (const float*)d_in[13];
    const float* lw1 = (const float*)d_in[14];
    const float* lb1 = (const float*)d_in[15];
    const float* lw2 = (const float*)d_in[16];
    const float* lb2 = (const float*)d_in[17];
    float* out = (float*)d_out;
    float* pa  = (float*)d_ws;          // 2 floats/px = 8 MB scratch

    dim3 grid(IMG / TSW, IMG / TSH);    // 32 x 64 = 2048 blocks per kernel
    unet_half<0><<<grid, 256, 0, stream>>>(x,  w1a, b1a, w2a, b2a, w3a, b3a,
                                           lw1, lb1, lw2, lb2, pa, out);
    unet_half<1><<<grid, 256, 0, stream>>>(x2, w1b, b1b, w2b, b2b, w3b, b3b,
                                           lw1, lb1, lw2, lb2, pa, out);
}